// Round 5
// baseline (256.935 us; speedup 1.0000x reference)
//
#include <hip/hip_runtime.h>
#include <climits>

// StreamingRhythmProjector: B=4096 rows x U=2048 units, one 256-thread
// block per row (grid = B, like R9).
// R13: UNCONDITIONAL, control-flow-free load stream.
// Evidence: R9/R10/R11/R12 (stores path, occupancy geometry, issue
// batching) are all pinned at 2.35 TB/s / ~9450 cy/row while moving 34 KB
// /row (3.6 B/cy/CU) with VALUBusy 11% -> memory stalls dominate and no
// throughput resource is saturated. Common trait of all four: loads are
// predicated on `visible` (probe->ballot->conditional loads, early-exit
// scan), so the load stream is control-dependent, shallow, and per-row
// variable (ragged drain, occupancy 57%).
// R13 changes:
//  - ALL 8 data float4s (full row, both chunks, NO visible predication) +
//    probe word + open-run chunk 0 are issued back-to-back at the top;
//    probe/scan/commit logic resolves while ~8KB/wave is in flight;
//    masking happens in compute only. Over-read beyond visible: fetch
//    ~45 -> ~110 MB requested (L3 absorbs part) -- intentional trade.
//  - Uniform read work per row -> no ragged drain from visible variance.
//  - launch_bounds(256,4): 128-VGPR cap so the ~10 in-flight float4s
//    plus sv arrays cannot spill (R10 lesson). 16 waves/CU with 8KB/wave
//    outstanding is ample concurrency if the theory holds.
// Discriminator: dur 63 -> 38-48us (theory right) vs 80-95us (true
// ~2.4 TB/s pattern cap -> revert to R9, near-roofline).

constexpr int UNITS = 2048;
constexpr int BLOCK = 256;

typedef float f32x4 __attribute__((ext_vector_type(4)));

static __device__ __forceinline__ float waveSum(float v) {
#pragma unroll
  for (int m = 1; m < 64; m <<= 1) v += __shfl_xor(v, m, 64);
  return v;  // all lanes hold the sum
}

__global__ __launch_bounds__(BLOCK, 4) void rhythm_kernel(
    const float* __restrict__ dur_anchor,    // [B,U]
    const float* __restrict__ unit_mask,     // [B,U] prefix mask (0/1)
    const float* __restrict__ speech_budget, // [B]
    const float* __restrict__ pause_budget,  // [B]
    const float* __restrict__ dur_logratio,  // [B,U]
    const float* __restrict__ pause_weight,  // [B,U]
    const float* __restrict__ boundary,      // [B,U]
    const float* __restrict__ phase_ptr,     // [B]
    const float* __restrict__ backlog,       // [B]
    const float* __restrict__ clock_delta,   // [B]
    const int*   __restrict__ commit_front,  // [B]
    const int*   __restrict__ open_run,      // [B,U]
    float* __restrict__ out,                 // f32, 3*B*U + 4*B
    int B) {
  const int row = blockIdx.x;
  const int t = threadIdx.x;
  const int wv = t >> 6, ln = t & 63;
  const size_t base = (size_t)row * UNITS;

  // ---- issue EVERYTHING up front: 8 data float4s + probe + open ch0 ----
  const int e0 = 4 * t;            // chunk-0 element in [0,1024)
  const int e1 = 1024 + 4 * t;     // chunk-1 element in [1024,2048)
  const float4 a0 = *(const float4*)(dur_anchor   + base + e0);
  const float4 a1 = *(const float4*)(dur_anchor   + base + e1);
  const float4 l0 = *(const float4*)(dur_logratio + base + e0);
  const float4 l1 = *(const float4*)(dur_logratio + base + e1);
  const float4 p0 = *(const float4*)(pause_weight + base + e0);
  const float4 p1 = *(const float4*)(pause_weight + base + e1);
  const float4 b0 = *(const float4*)(boundary     + base + e0);
  const float4 b1 = *(const float4*)(boundary     + base + e1);
  const float v1 = unit_mask[base + 64 * ((ln < 32) ? ln : 0) + 63];
  const int4 oo = *(const int4*)(open_run + base + 4 * ln);

  // per-row scalars (tiny, cached)
  const int prev = commit_front[row];
  const float sb = speech_budget[row];
  const float pb = pause_budget[row];

  // ---- probe `visible` (consumes only v1; data loads still in flight) ----
  int visible;
  {
    const int c1 = __popcll(__ballot((ln < 32) && (v1 > 0.5f)));
    if (c1 == 32) {
      visible = 2048;
    } else {
      const int s = 64 * c1;                       // s <= 1984, s+63 <= 2047
      const float v2 = unit_mask[base + s + ln];
      visible = s + __popcll(__ballot(v2 > 0.5f));
    }
  }

  // ---- first open index in [0, visible); chunk 0 already in regs ----
  int min_open = INT_MAX;
  {
    const int e = 4 * ln;
    int lm = INT_MAX;
    if (oo.w > 0 && e + 3 < visible) lm = e + 3;
    if (oo.z > 0 && e + 2 < visible) lm = e + 2;
    if (oo.y > 0 && e + 1 < visible) lm = e + 1;
    if (oo.x > 0 && e < visible)     lm = e;
    const unsigned long long bb = __ballot(lm != INT_MAX);
    if (bb) {
      min_open = __shfl(lm, (int)__ffsll(bb) - 1, 64);
    } else {
      for (int cs = 256; cs < visible; cs += 256) {  // rare (10% density)
        const int e2 = cs + 4 * ln;
        int4 o4 = make_int4(0, 0, 0, 0);
        if (e2 < visible) o4 = *(const int4*)(open_run + base + e2);
        int lm2 = INT_MAX;
        if (o4.w > 0 && e2 + 3 < visible) lm2 = e2 + 3;
        if (o4.z > 0 && e2 + 2 < visible) lm2 = e2 + 2;
        if (o4.y > 0 && e2 + 1 < visible) lm2 = e2 + 1;
        if (o4.x > 0 && e2 < visible)     lm2 = e2;
        const unsigned long long bb2 = __ballot(lm2 != INT_MAX);
        if (bb2) {
          min_open = __shfl(lm2, (int)__ffsll(bb2) - 1, 64);
          break;
        }
      }
    }
  }

  // ---- commit candidate + bval (issued before compute; tiny) ----
  const int closed = (min_open == INT_MAX) ? visible : min_open;
  const int relcap = max(visible - 2, 0);             // TAIL_HOLD_UNITS
  const int cand0 = min(relcap, closed);
  const float bval = boundary[base + min(max(cand0 - 1, 0), UNITS - 1)];

  // ---- pass 1 compute: masked, from registers ----
  float sv_sr[8];  // masked speech_raw
  float sv_sc[8];  // masked pause score
  float sum_sr = 0.f, sum_sc = 0.f;
  {
    const float av[8] = {a0.x, a0.y, a0.z, a0.w, a1.x, a1.y, a1.z, a1.w};
    const float lv[8] = {l0.x, l0.y, l0.z, l0.w, l1.x, l1.y, l1.z, l1.w};
    const float pv[8] = {p0.x, p0.y, p0.z, p0.w, p1.x, p1.y, p1.z, p1.w};
    const float bv[8] = {b0.x, b0.y, b0.z, b0.w, b1.x, b1.y, b1.z, b1.w};
#pragma unroll
    for (int k = 0; k < 8; ++k) {
      const int e = (k < 4) ? (e0 + k) : (e1 + k - 4);
      const float m = (e < visible) ? 1.0f : 0.0f;
      const float a = fmaxf(av[k], 1.0f);                      // MIN_SPEECH_FRAMES
      const float sr = fmaxf(fminf(a * __expf(lv[k]), 3.0f * a), 1.0f) * m;
      const float sc = fmaxf(pv[k], 0.0f) * (0.5f + bv[k]) * m;
      sv_sr[k] = sr;
      sv_sc[k] = sc;
      sum_sr += sr;
      sum_sc += sc;
    }
  }

  // ---- reduction (the ONLY barrier): ts, tc ----
  __shared__ float sf[2][4];
  const float r0 = waveSum(sum_sr);
  const float r1 = waveSum(sum_sc);
  if (ln == 0) { sf[0][wv] = r0; sf[1][wv] = r1; }
  __syncthreads();

  const float ts = sf[0][0] + sf[0][1] + sf[0][2] + sf[0][3];
  const float tc = sf[1][0] + sf[1][1] + sf[1][2] + sf[1][3];
  const float tm = (float)visible;  // sum of prefix mask, exact

  // ---- commit frontier finalize ----
  int cand = cand0;
  if (cand0 > 0 && cand0 < visible && bval < 0.45f)   // BOUNDARY_COMMIT_THRESHOLD
    cand = max(prev, cand0 - 1);
  const int commit = max(prev, cand);

  const float sscale = sb / fmaxf(ts, 1e-6f);
  const bool usefb = !(tc > 0.0f);
  const float pscale = pb / fmaxf(tc, 1e-6f);
  const float fbw = pb / fmaxf(tm, 1.0f);
  // analytic effective total (linearity): Sum eff = sscale*ts + pscale*tc
  const float eff_tot = usefb ? (sscale * ts + fbw * tm) : (sscale * ts + pscale * tc);

  // ---- pass 2: pure compute + stores from registers ----
  float* __restrict__ out_speech = out;
  float* __restrict__ out_pause  = out + (size_t)B * UNITS;
  float* __restrict__ out_eff    = out + 2 * (size_t)B * UNITS;

#pragma unroll
  for (int c = 0; c < 2; ++c) {
    const int eb = c * 1024 + 4 * t;
    f32x4 s4, q4, e4;
#pragma unroll
    for (int j = 0; j < 4; ++j) {
      const int k = c * 4 + j;
      const float m = (eb + j < visible) ? 1.0f : 0.0f;
      const float speech = sv_sr[k] * sscale;          // sr already masked
      const float pause = usefb ? (m * fbw) : (sv_sc[k] * pscale);
      s4[j] = speech;
      q4[j] = pause;
      e4[j] = speech + pause;                          // both already masked
    }
    *(f32x4*)(out_speech + base + eb) = s4;
    *(f32x4*)(out_pause  + base + eb) = q4;
    *(f32x4*)(out_eff    + base + eb) = e4;
  }

  // ---- wave 0 alone: tiny [prev,commit) range sums (cache-hot recompute) ----
  if (wv == 0) {
    float src_rng = 0.f, eff_rng = 0.f;
    if (commit > prev) {
      for (int i = prev + ln; i < commit; i += 64) {   // all i < visible here
        const float a = dur_anchor[base + i];
        const float l = dur_logratio[base + i];
        const float p = pause_weight[base + i];
        const float bo = boundary[base + i];
        src_rng += a;
        const float aa = fmaxf(a, 1.0f);
        const float sr = fmaxf(fminf(aa * __expf(l), 3.0f * aa), 1.0f);
        const float sc = fmaxf(p, 0.0f) * (0.5f + bo);
        eff_rng += sr * sscale + (usefb ? fbw : sc * pscale);
      }
    }
    const float srcp = waveSum(src_rng);
    const float execp = waveSum(eff_rng);

    if (ln == 0) {
      const float pp = phase_ptr[row];
      const float bl = backlog[row];
      const float cd = clock_delta[row];
      const bool adv = commit > prev;
      const float nclock = adv ? (cd + (execp - srcp)) : cd;
      const float nback = adv ? fmaxf(nclock, 0.0f) : bl;
      const float vt = fmaxf(eff_tot, 1.0f);
      const float nphase =
          adv ? fminf(fmaxf(pp + execp / vt, 0.0f), 1.0f) : pp;
      const size_t o = 3 * (size_t)B * UNITS;
      out[o + row] = (float)commit;
      out[o + (size_t)B + row] = nphase;
      out[o + 2 * (size_t)B + row] = nback;
      out[o + 3 * (size_t)B + row] = nclock;
    }
  }
}

extern "C" void kernel_launch(void* const* d_in, const int* in_sizes, int n_in,
                              void* d_out, int out_size, void* d_ws, size_t ws_size,
                              hipStream_t stream) {
  const int B = in_sizes[7];  // phase_ptr length
  rhythm_kernel<<<dim3(B), dim3(BLOCK), 0, stream>>>(
      (const float*)d_in[0],   // dur_anchor_src
      (const float*)d_in[1],   // unit_mask
      (const float*)d_in[2],   // speech_budget_win
      (const float*)d_in[3],   // pause_budget_win
      (const float*)d_in[4],   // dur_logratio_unit
      (const float*)d_in[5],   // pause_weight_unit
      (const float*)d_in[6],   // boundary_latent
      (const float*)d_in[7],   // phase_ptr
      (const float*)d_in[8],   // backlog
      (const float*)d_in[9],   // clock_delta
      (const int*)d_in[10],    // commit_frontier
      (const int*)d_in[11],    // open_run_mask
      (float*)d_out, B);
}

// Round 6
// 256.792 us; speedup vs baseline: 1.0006x; 1.0006x over previous
//
#include <hip/hip_runtime.h>
#include <climits>

// StreamingRhythmProjector: B=4096 rows x U=2048 units.
// R14: WAVE-PER-ROW, ZERO BARRIERS, ZERO LDS.
// Evidence trail: R9-R13 (stores path, occupancy geometry, issue batching,
// unconditional deep bursts) all pin at ~2.2-2.35 TB/s; R13 proved more
// in-flight bytes does NOT raise throughput (time strictly tracks bytes at
// the pinned rate, marginal read BW ~1.6 TB/s). Shared trait of all five:
// block-wide barrier convoy -- all waves burst-load, drain vmcnt at
// __syncthreads, compute, store in lockstep -> read-pipe duty cycle ~35%,
// and 6.3 TB/s x 0.35 = the observed 2.2 TB/s.
// R14 removes the convoy:
//  - one wave owns one full row (32 elem/lane); every reduction becomes
//    waveSum/ballot (already wave-scoped) -> NO __syncthreads, NO LDS.
//  - 256-thread blocks = 4 independent waves/rows; grid = B/4 = 1024 =
//    exactly 4 blocks/CU -> whole grid resident, waves free-run & retire
//    independently (no ragged rounds).
//  - pass-1 reads: 8 chunks of 256 elems, 2-deep prefetch pipeline
//    (predicated on visible -> fetch stays minimal per R13's lesson),
//    keeping reads outstanding through compute on every wave.
//  - launch_bounds(256,4): 128-VGPR cap; est. ~115 live (sv 64 + dbuf 32
//    + misc). WRITE_SIZE > 110 MB next round = spill alarm.

constexpr int UNITS = 2048;
constexpr int BLOCK = 256;
constexpr int ROWS_PER_BLOCK = 4;  // one per wave

typedef float f32x4 __attribute__((ext_vector_type(4)));

static __device__ __forceinline__ float waveSum(float v) {
#pragma unroll
  for (int m = 1; m < 64; m <<= 1) v += __shfl_xor(v, m, 64);
  return v;  // all lanes hold the sum
}

__global__ __launch_bounds__(BLOCK, 4) void rhythm_kernel(
    const float* __restrict__ dur_anchor,    // [B,U]
    const float* __restrict__ unit_mask,     // [B,U] prefix mask (0/1)
    const float* __restrict__ speech_budget, // [B]
    const float* __restrict__ pause_budget,  // [B]
    const float* __restrict__ dur_logratio,  // [B,U]
    const float* __restrict__ pause_weight,  // [B,U]
    const float* __restrict__ boundary,      // [B,U]
    const float* __restrict__ phase_ptr,     // [B]
    const float* __restrict__ backlog,       // [B]
    const float* __restrict__ clock_delta,   // [B]
    const int*   __restrict__ commit_front,  // [B]
    const int*   __restrict__ open_run,      // [B,U]
    float* __restrict__ out,                 // f32, 3*B*U + 4*B
    int B) {
  const int t = threadIdx.x;
  const int wv = t >> 6, ln = t & 63;
  const int row = blockIdx.x * ROWS_PER_BLOCK + wv;
  if (row >= B) return;  // whole-wave uniform; no barriers below
  const size_t base = (size_t)row * UNITS;

  // per-row scalars
  const int prev = commit_front[row];
  const float sb = speech_budget[row];
  const float pb = pause_budget[row];

  // ---- probe `visible` from the prefix mask ----
  int visible;
  {
    const float v1 = unit_mask[base + 64 * ((ln < 32) ? ln : 0) + 63];
    const int c1 = __popcll(__ballot((ln < 32) && (v1 > 0.5f)));
    if (c1 == 32) {
      visible = 2048;
    } else {
      const int s = 64 * c1;                       // s <= 1984, s+63 <= 2047
      const float v2 = unit_mask[base + s + ln];
      visible = s + __popcll(__ballot(v2 > 0.5f));
    }
  }

  // ---- early-exit scan for first open index in [0, visible) ----
  int min_open = INT_MAX;
  for (int cs = 0; cs < visible; cs += 256) {
    const int e = cs + 4 * ln;                     // e+3 <= 2047 always
    int4 o4 = make_int4(0, 0, 0, 0);
    if (e < visible) o4 = *(const int4*)(open_run + base + e);
    int lm = INT_MAX;
    if (o4.w > 0 && e + 3 < visible) lm = e + 3;
    if (o4.z > 0 && e + 2 < visible) lm = e + 2;
    if (o4.y > 0 && e + 1 < visible) lm = e + 1;
    if (o4.x > 0 && e < visible) lm = e;
    const unsigned long long bb = __ballot(lm != INT_MAX);
    if (bb) {  // lanes ascend in idx; first set lane holds the chunk min
      min_open = __shfl(lm, (int)__ffsll(bb) - 1, 64);
      break;
    }
  }

  // ---- commit candidate + bval (issued before pass 1; resolves under it) --
  const int closed = (min_open == INT_MAX) ? visible : min_open;
  const int cand0 = min(max(visible - 2, 0), closed);  // TAIL_HOLD_UNITS
  const float bval = boundary[base + min(max(cand0 - 1, 0), UNITS - 1)];

  // ---- pass 1: 8 chunks x 256 elems (4/lane), 2-deep prefetch pipeline ----
  float sr_[8][4];  // masked speech_raw
  float sc_[8][4];  // masked pause score
  float sum_sr = 0.f, sum_sc = 0.f;

  float4 Ab[2], Lb[2], Pb[2], Bb[2];
  auto loadChunk = [&](int c, int slot) {
    const int e = c * 256 + 4 * ln;
    const float4 z = {0.f, 0.f, 0.f, 0.f};
    Ab[slot] = z; Lb[slot] = z; Pb[slot] = z; Bb[slot] = z;
    if (e < visible) {
      Ab[slot] = *(const float4*)(dur_anchor   + base + e);
      Lb[slot] = *(const float4*)(dur_logratio + base + e);
      Pb[slot] = *(const float4*)(pause_weight + base + e);
      Bb[slot] = *(const float4*)(boundary     + base + e);
    }
  };

  loadChunk(0, 0);
  loadChunk(1, 1);
#pragma unroll
  for (int c = 0; c < 8; ++c) {
    const float4 a4 = Ab[c & 1];  // waits only on chunk c's loads
    const float4 l4 = Lb[c & 1];
    const float4 p4 = Pb[c & 1];
    const float4 b4 = Bb[c & 1];
    if (c + 2 < 8) loadChunk(c + 2, c & 1);  // refill slot, 2 ahead
    const int e = c * 256 + 4 * ln;
    const float av[4] = {a4.x, a4.y, a4.z, a4.w};
    const float lv[4] = {l4.x, l4.y, l4.z, l4.w};
    const float pv[4] = {p4.x, p4.y, p4.z, p4.w};
    const float bv[4] = {b4.x, b4.y, b4.z, b4.w};
#pragma unroll
    for (int j = 0; j < 4; ++j) {
      const float m = (e + j < visible) ? 1.0f : 0.0f;
      const float a = fmaxf(av[j], 1.0f);                      // MIN_SPEECH_FRAMES
      const float sr = fmaxf(fminf(a * __expf(lv[j]), 3.0f * a), 1.0f) * m;
      const float sc = fmaxf(pv[j], 0.0f) * (0.5f + bv[j]) * m;
      sr_[c][j] = sr;
      sc_[c][j] = sc;
      sum_sr += sr;
      sum_sc += sc;
    }
  }

  // ---- totals: pure in-wave reduction (NO barrier, NO LDS) ----
  const float ts = waveSum(sum_sr);
  const float tc = waveSum(sum_sc);
  const float tm = (float)visible;  // sum of prefix mask, exact

  // ---- commit frontier finalize ----
  int cand = cand0;
  if (cand0 > 0 && cand0 < visible && bval < 0.45f)   // BOUNDARY_COMMIT_THRESHOLD
    cand = max(prev, cand0 - 1);
  const int commit = max(prev, cand);

  const float sscale = sb / fmaxf(ts, 1e-6f);
  const bool usefb = !(tc > 0.0f);
  const float pscale = pb / fmaxf(tc, 1e-6f);
  const float fbw = pb / fmaxf(tm, 1.0f);
  // analytic effective total (linearity): Sum eff = sscale*ts + pscale*tc
  const float eff_tot = usefb ? (sscale * ts + fbw * tm) : (sscale * ts + pscale * tc);

  // ---- pass 2: pure compute + stores from registers ----
  float* __restrict__ out_speech = out;
  float* __restrict__ out_pause  = out + (size_t)B * UNITS;
  float* __restrict__ out_eff    = out + 2 * (size_t)B * UNITS;

#pragma unroll
  for (int c = 0; c < 8; ++c) {
    const int e = c * 256 + 4 * ln;
    f32x4 s4, q4, e4;
#pragma unroll
    for (int j = 0; j < 4; ++j) {
      const float m = (e + j < visible) ? 1.0f : 0.0f;
      const float speech = sr_[c][j] * sscale;         // sr already masked
      const float pause = usefb ? (m * fbw) : (sc_[c][j] * pscale);
      s4[j] = speech;
      q4[j] = pause;
      e4[j] = speech + pause;                          // both already masked
    }
    *(f32x4*)(out_speech + base + e) = s4;
    *(f32x4*)(out_pause  + base + e) = q4;
    *(f32x4*)(out_eff    + base + e) = e4;
  }

  // ---- per-wave tail: tiny [prev,commit) range sums (cache-hot re-read) ----
  float src_rng = 0.f, eff_rng = 0.f;
  if (commit > prev) {
    for (int i = prev + ln; i < commit; i += 64) {     // all i < visible here
      const float a = dur_anchor[base + i];
      const float l = dur_logratio[base + i];
      const float p = pause_weight[base + i];
      const float bo = boundary[base + i];
      src_rng += a;
      const float aa = fmaxf(a, 1.0f);
      const float sr = fmaxf(fminf(aa * __expf(l), 3.0f * aa), 1.0f);
      const float sc = fmaxf(p, 0.0f) * (0.5f + bo);
      eff_rng += sr * sscale + (usefb ? fbw : sc * pscale);
    }
  }
  const float srcp = waveSum(src_rng);
  const float execp = waveSum(eff_rng);

  if (ln == 0) {
    const float pp = phase_ptr[row];
    const float bl = backlog[row];
    const float cd = clock_delta[row];
    const bool adv = commit > prev;
    const float nclock = adv ? (cd + (execp - srcp)) : cd;
    const float nback = adv ? fmaxf(nclock, 0.0f) : bl;
    const float vt = fmaxf(eff_tot, 1.0f);
    const float nphase =
        adv ? fminf(fmaxf(pp + execp / vt, 0.0f), 1.0f) : pp;
    const size_t o = 3 * (size_t)B * UNITS;
    out[o + row] = (float)commit;
    out[o + (size_t)B + row] = nphase;
    out[o + 2 * (size_t)B + row] = nback;
    out[o + 3 * (size_t)B + row] = nclock;
  }
}

extern "C" void kernel_launch(void* const* d_in, const int* in_sizes, int n_in,
                              void* d_out, int out_size, void* d_ws, size_t ws_size,
                              hipStream_t stream) {
  const int B = in_sizes[7];  // phase_ptr length
  const int nb = (B + ROWS_PER_BLOCK - 1) / ROWS_PER_BLOCK;
  rhythm_kernel<<<dim3(nb), dim3(BLOCK), 0, stream>>>(
      (const float*)d_in[0],   // dur_anchor_src
      (const float*)d_in[1],   // unit_mask
      (const float*)d_in[2],   // speech_budget_win
      (const float*)d_in[3],   // pause_budget_win
      (const float*)d_in[4],   // dur_logratio_unit
      (const float*)d_in[5],   // pause_weight_unit
      (const float*)d_in[6],   // boundary_latent
      (const float*)d_in[7],   // phase_ptr
      (const float*)d_in[8],   // backlog
      (const float*)d_in[9],   // clock_delta
      (const int*)d_in[10],    // commit_frontier
      (const int*)d_in[11],    // open_run_mask
      (float*)d_out, B);
}